// Round 4
// baseline (262.785 us; speedup 1.0000x reference)
//
#include <hip/hip_runtime.h>
#include <hip/hip_bf16.h>

#define N_EMBD 1024
#define T_SEQ  2048
#define BATCH  2
#define NHEAD  16
#define DKH    64
#define MTOK   (BATCH * T_SEQ)   // 4096

typedef __attribute__((ext_vector_type(8))) short short8;   // 8 x bf16
typedef __attribute__((ext_vector_type(4))) short short4v;  // 4 x bf16
typedef __attribute__((ext_vector_type(4))) float floatx4;  // MFMA C/D

#define QSCALE 0.18033688011112042f   // 0.125 * log2(e), folded into Q

static __device__ __forceinline__ short bf16_of(float f) {
    union { float f; unsigned u; } x; x.f = f;
    unsigned r = (x.u + 0x7fff + ((x.u >> 16) & 1)) >> 16;
    return (short)r;
}

static __device__ __forceinline__ void async_copy16(const void* g, void* l) {
    __builtin_amdgcn_global_load_lds(
        (const __attribute__((address_space(1))) void*)g,
        (__attribute__((address_space(3))) void*)l,
        16, 0, 0);
}

// ---------------- fused fp32 -> bf16 convert for all 5 tensors ----------------
__global__ __launch_bounds__(256) void cvt_all(
    const float* __restrict__ x,  const float* __restrict__ Wq,
    const float* __restrict__ Wk, const float* __restrict__ Wv,
    const float* __restrict__ Wo,
    short* __restrict__ xb, short* __restrict__ Wqkvb, short* __restrict__ Wob) {
    int b = blockIdx.x;
    const float* src; short* dst; long base;
    if (b < 4096) { src = x; dst = xb; base = (long)b * 1024; }
    else {
        int r   = (b - 4096) >> 10;
        base    = (long)((b - 4096) & 1023) * 1024;
        if (r == 0)      { src = Wq; dst = Wqkvb;           }
        else if (r == 1) { src = Wk; dst = Wqkvb + 1048576; }
        else if (r == 2) { src = Wv; dst = Wqkvb + 2097152; }
        else             { src = Wo; dst = Wob;             }
    }
    long i = base + threadIdx.x * 4;
    float4 v = *(const float4*)(src + i);
    short4 o;
    o.x = bf16_of(v.x); o.y = bf16_of(v.y); o.z = bf16_of(v.z); o.w = bf16_of(v.w);
    *(short4*)(dst + i) = o;
}

// ---------------- GEMM: C[m][n] = sum_k A[m][k] * Bw[n][k] + bias[n] ----------------
// MODE 0: QKV epilogue (Q scaled by QSCALE; scatter Q/K [BH,T,64], Vt [BH,64,T])
// MODE 1: proj epilogue (fp32 out [M,1024])
template<int MODE>
__global__ __launch_bounds__(256) void gemm_bt(
    const short* __restrict__ A, const short* __restrict__ Bw,
    const float* __restrict__ b0, const float* __restrict__ b1, const float* __restrict__ b2,
    short* __restrict__ outQ, short* __restrict__ outK, short* __restrict__ outV,
    float* __restrict__ outP, int K)
{
    __shared__ short As[128 * 32];
    __shared__ short Bs[128 * 32];
    const int tid  = threadIdx.x;
    const int w    = tid >> 6, lane = tid & 63;
    const int quad = lane >> 4, lr = lane & 15;
    const int wm   = (w & 1) * 64, wn = (w >> 1) * 64;
    const long m0  = (long)blockIdx.y * 128, n0 = (long)blockIdx.x * 128;

    floatx4 acc[4][4] = {};

    const int srow = lane >> 2;          // 0..15
    const int scol = (lane & 3) * 8;     // 0,8,16,24
    const short* gA = A  + (m0 + w * 16 + srow) * (long)K + scol;
    const short* gB = Bw + (n0 + w * 16 + srow) * (long)K + scol;

    for (int kt = 0; kt < K; kt += 32) {
        async_copy16(gA + kt,            As + w * 512);
        async_copy16(gA + kt + 64L * K,  As + (w + 4) * 512);
        async_copy16(gB + kt,            Bs + w * 512);
        async_copy16(gB + kt + 64L * K,  Bs + (w + 4) * 512);
        __syncthreads();

        const short8* As8 = (const short8*)As;
        const short8* Bs8 = (const short8*)Bs;
        short8 af[4], bf[4];
#pragma unroll
        for (int i = 0; i < 4; ++i) af[i] = As8[(wm + i * 16 + lr) * 4 + quad];
#pragma unroll
        for (int j = 0; j < 4; ++j) bf[j] = Bs8[(wn + j * 16 + lr) * 4 + quad];
#pragma unroll
        for (int i = 0; i < 4; ++i)
#pragma unroll
            for (int j = 0; j < 4; ++j)
                acc[i][j] = __builtin_amdgcn_mfma_f32_16x16x32_bf16(af[i], bf[j], acc[i][j], 0, 0, 0);
        __syncthreads();
    }

#pragma unroll
    for (int i = 0; i < 4; ++i) {
#pragma unroll
        for (int j = 0; j < 4; ++j) {
#pragma unroll
            for (int r = 0; r < 4; ++r) {
                long m = m0 + wm + i * 16 + quad * 4 + r;   // token index
                long n = n0 + wn + j * 16 + lr;             // output feature
                float v = acc[i][j][r];
                if (MODE == 0) {
                    int sel = (int)(n >> 10);
                    int nn  = (int)(n & 1023);
                    v += (sel == 0 ? b0[nn] : (sel == 1 ? b1[nn] : b2[nn]));
                    int  h  = nn >> 6, d = nn & 63;
                    long b  = m >> 11, t = m & 2047;
                    long bh = b * NHEAD + h;
                    if (sel == 0)      outQ[(bh * T_SEQ + t) * DKH + d] = bf16_of(v * QSCALE);
                    else if (sel == 1) outK[(bh * T_SEQ + t) * DKH + d] = bf16_of(v);
                    else               outV[(bh * DKH + d) * T_SEQ + t] = bf16_of(v);
                } else {
                    v += b0[(int)n];
                    outP[m * N_EMBD + n] = v;
                }
            }
        }
    }
}

// ---------------- flash attention, S^T formulation: no LDS in stage loop ----------------
// Block = one 64-row q-tile of one bh. 4 waves = 2 q-subtiles (32 rows) x 2 key-halves.
// S^T = mfma(K-frag, Q-frag) -> C-layout (col=q=lr, row=key=quad*4+r) which IS the
// X-operand layout for O^T = mfma(V^T-frag, P-frag) under the per-stage key
// permutation key = blk*16 + quad*4 + r (compensated in the V^T loads).
// Fixed-max softmax (Q pre-scaled by 0.125*log2e): P = exp2(S).
__global__ __launch_bounds__(256) void attn_kernel(
    const short* __restrict__ Q, const short* __restrict__ Kb,
    const short* __restrict__ Vt, short* __restrict__ Y)
{
    __shared__ float Ob[2][32][68];        // half-1 partial O^T (padded row: 68 floats)
    __shared__ float Lb[2][32];            // half-1 partial row sums

    const int tid  = threadIdx.x;
    const int w    = tid >> 6, lane = tid & 63;
    const int quad = lane >> 4, lr = lane & 15;
    const int qs   = w & 1, half = w >> 1;

    const int id = blockIdx.x;
    const int qt = 31 - (id >> 5);         // big tiles dispatched first
    const int bh = id & 31;

    const short* Qp = Q  + (long)bh * (T_SEQ * DKH);
    const short* Kp = Kb + (long)bh * (T_SEQ * DKH);
    const short* Vp = Vt + (long)bh * (DKH * T_SEQ);

    const int qrb = qt * 64 + qs * 32;     // wave's 32 q-rows

    short8 qf[2][2];                       // X-operand: Q[q=lr][c*32+quad*8..]
#pragma unroll
    for (int m = 0; m < 2; ++m)
#pragma unroll
        for (int c = 0; c < 2; ++c)
            qf[m][c] = *(const short8*)(Qp + (long)(qrb + m * 16 + lr) * DKH + c * 32 + quad * 8);

    floatx4 o[2][4] = {};                  // O^T accum: rows d, cols q
    float rs[2] = {0.f, 0.f};

    const int S_tot = 2 * qt + qs + 1;     // 32-key stages for these rows
    const int h0 = (S_tot + 1) >> 1;
    const int sb = half ? h0 : 0;
    const int se = half ? S_tot : h0;

    short8 kbn[2][2];                      // K prefetch (A-operand: K[key=lr][...])
    if (sb < se) {
        const int k0 = sb * 32;
#pragma unroll
        for (int blk = 0; blk < 2; ++blk)
#pragma unroll
            for (int c = 0; c < 2; ++c)
                kbn[blk][c] = *(const short8*)(Kp + (long)(k0 + blk * 16 + lr) * DKH + c * 32 + quad * 8);
    }

    for (int s = sb; s < se; ++s) {
        const int k0 = s * 32;
        short8 ka[2][2];
#pragma unroll
        for (int blk = 0; blk < 2; ++blk)
#pragma unroll
            for (int c = 0; c < 2; ++c) ka[blk][c] = kbn[blk][c];
        if (s + 1 < se) {
            const int k1 = (s + 1) * 32;
#pragma unroll
            for (int blk = 0; blk < 2; ++blk)
#pragma unroll
                for (int c = 0; c < 2; ++c)
                    kbn[blk][c] = *(const short8*)(Kp + (long)(k1 + blk * 16 + lr) * DKH + c * 32 + quad * 8);
        }

        // V^T A-fragments with permuted keys: element (blk*4+r) <- key k0+blk*16+quad*4+r
        short8 va[4];
#pragma unroll
        for (int d = 0; d < 4; ++d) {
            const short* vrow = Vp + (long)(d * 16 + lr) * T_SEQ + k0 + quad * 4;
            union { short8 v; struct { short4v a, b; } h; } u;
            u.h.a = *(const short4v*)(vrow);
            u.h.b = *(const short4v*)(vrow + 16);
            va[d] = u.v;
        }

        // S^T = K Q^T : rows=key, cols=q
        floatx4 sc[2][2];
#pragma unroll
        for (int m = 0; m < 2; ++m)
#pragma unroll
            for (int blk = 0; blk < 2; ++blk) {
                floatx4 z = {};
                z = __builtin_amdgcn_mfma_f32_16x16x32_bf16(ka[blk][0], qf[m][0], z, 0, 0, 0);
                z = __builtin_amdgcn_mfma_f32_16x16x32_bf16(ka[blk][1], qf[m][1], z, 0, 0, 0);
                sc[m][blk] = z;
            }

        if (s == S_tot - 1) {              // wave-uniform diagonal stage
#pragma unroll
            for (int m = 0; m < 2; ++m)
#pragma unroll
                for (int blk = 0; blk < 2; ++blk)
#pragma unroll
                    for (int r = 0; r < 4; ++r) {
                        int key = k0 + blk * 16 + quad * 4 + r;
                        if (key > qrb + m * 16 + lr) sc[m][blk][r] = -INFINITY;
                    }
        }

        // P = exp2(S^T), pack in-register into X-operand fragments
        short8 pa[2];
#pragma unroll
        for (int m = 0; m < 2; ++m) {
            union { short8 v; short e[8]; } pu;
#pragma unroll
            for (int blk = 0; blk < 2; ++blk)
#pragma unroll
                for (int r = 0; r < 4; ++r) {
                    float p = __builtin_amdgcn_exp2f(sc[m][blk][r]);
                    rs[m] += p;
                    union { float f; unsigned u; } cc; cc.f = p;
                    pu.e[blk * 4 + r] = (short)((cc.u + 0x8000u) >> 16);
                }
            pa[m] = pu.v;
        }

        // O^T += V^T P
#pragma unroll
        for (int m = 0; m < 2; ++m)
#pragma unroll
            for (int d = 0; d < 4; ++d)
                o[m][d] = __builtin_amdgcn_mfma_f32_16x16x32_bf16(va[d], pa[m], o[m][d], 0, 0, 0);
    }

    // full row sums (row = q = lr): reduce across the 4 quads
#pragma unroll
    for (int m = 0; m < 2; ++m) {
        rs[m] += __shfl_xor(rs[m], 16, 64);
        rs[m] += __shfl_xor(rs[m], 32, 64);
    }

    if (half == 1) {
#pragma unroll
        for (int m = 0; m < 2; ++m) {
#pragma unroll
            for (int d = 0; d < 4; ++d)
                *(floatx4*)&Ob[qs][m * 16 + lr][d * 16 + quad * 4] = o[m][d];
            Lb[qs][m * 16 + lr] = rs[m];   // all quads write same value (benign)
        }
    }
    __syncthreads();
    if (half == 0) {
        const long trow0 = (long)(bh >> 4) * T_SEQ + qrb;
        const int  hcol  = (bh & 15) * DKH;
#pragma unroll
        for (int m = 0; m < 2; ++m) {
            float l   = rs[m] + Lb[qs][m * 16 + lr];
            float inv = 1.f / l;
            long  yb  = (trow0 + m * 16 + lr) * N_EMBD + hcol;
#pragma unroll
            for (int d = 0; d < 4; ++d) {
                floatx4 ob = *(const floatx4*)&Ob[qs][m * 16 + lr][d * 16 + quad * 4];
                short4v y4;
#pragma unroll
                for (int r = 0; r < 4; ++r) y4[r] = bf16_of((o[m][d][r] + ob[r]) * inv);
                *(short4v*)(Y + yb + d * 16 + quad * 4) = y4;
            }
        }
    }
}

extern "C" void kernel_launch(void* const* d_in, const int* in_sizes, int n_in,
                              void* d_out, int out_size, void* d_ws, size_t ws_size,
                              hipStream_t stream) {
    const float* x  = (const float*)d_in[0];
    const float* Wq = (const float*)d_in[1];
    const float* bq = (const float*)d_in[2];
    const float* Wk = (const float*)d_in[3];
    const float* bk = (const float*)d_in[4];
    const float* Wv = (const float*)d_in[5];
    const float* bv = (const float*)d_in[6];
    const float* Wo = (const float*)d_in[7];
    const float* bo = (const float*)d_in[8];
    float* out = (float*)d_out;

    char* ws = (char*)d_ws;
    short* xb    = (short*)(ws);                       // [4096,1024] bf16, 8MB; reused as Yb
    short* Wqkvb = (short*)(ws + (8L  << 20));         // [3072,1024] bf16, 6MB
    short* Wob   = (short*)(ws + (14L << 20));         // [1024,1024] bf16, 2MB
    short* Qb    = (short*)(ws + (16L << 20));         // [32,2048,64] bf16 (pre-scaled), 8MB
    short* Kbuf  = (short*)(ws + (24L << 20));         // [32,2048,64] bf16, 8MB
    short* Vtb   = (short*)(ws + (32L << 20));         // [32,64,2048] bf16, 8MB
    short* Yb    = xb;                                 // reuse (x dead after QKV GEMM)

    cvt_all<<<8192, 256, 0, stream>>>(x, Wq, Wk, Wv, Wo, xb, Wqkvb, Wob);

    gemm_bt<0><<<dim3(24, 32), 256, 0, stream>>>(xb, Wqkvb, bq, bk, bv,
                                                 Qb, Kbuf, Vtb, nullptr, N_EMBD);
    attn_kernel<<<1024, 256, 0, stream>>>(Qb, Kbuf, Vtb, Yb);
    gemm_bt<1><<<dim3(8, 32), 256, 0, stream>>>(Yb, Wob, bo, nullptr, nullptr,
                                                nullptr, nullptr, nullptr, out, N_EMBD);
}

// Round 5
// 189.220 us; speedup vs baseline: 1.3888x; 1.3888x over previous
//
#include <hip/hip_runtime.h>
#include <hip/hip_bf16.h>

#define N_EMBD 1024
#define T_SEQ  2048
#define BATCH  2
#define NHEAD  16
#define DKH    64
#define MTOK   (BATCH * T_SEQ)   // 4096

typedef __attribute__((ext_vector_type(8))) short short8;   // 8 x bf16
typedef __attribute__((ext_vector_type(4))) short short4v;  // 4 x bf16
typedef __attribute__((ext_vector_type(4))) float floatx4;  // MFMA C/D

#define QSCALE 0.18033688011112042f   // 0.125 * log2(e), folded into Q

static __device__ __forceinline__ short bf16_of(float f) {
    union { float f; unsigned u; } x; x.f = f;
    unsigned r = (x.u + 0x7fff + ((x.u >> 16) & 1)) >> 16;
    return (short)r;
}

static __device__ __forceinline__ void async_copy16(const void* g, void* l) {
    __builtin_amdgcn_global_load_lds(
        (const __attribute__((address_space(1))) void*)g,
        (__attribute__((address_space(3))) void*)l,
        16, 0, 0);
}

// ---------------- fused fp32 -> bf16 convert for all 5 tensors ----------------
__global__ __launch_bounds__(256) void cvt_all(
    const float* __restrict__ x,  const float* __restrict__ Wq,
    const float* __restrict__ Wk, const float* __restrict__ Wv,
    const float* __restrict__ Wo,
    short* __restrict__ xb, short* __restrict__ Wqkvb, short* __restrict__ Wob) {
    int b = blockIdx.x;
    const float* src; short* dst; long base;
    if (b < 4096) { src = x; dst = xb; base = (long)b * 1024; }
    else {
        int r   = (b - 4096) >> 10;
        base    = (long)((b - 4096) & 1023) * 1024;
        if (r == 0)      { src = Wq; dst = Wqkvb;           }
        else if (r == 1) { src = Wk; dst = Wqkvb + 1048576; }
        else if (r == 2) { src = Wv; dst = Wqkvb + 2097152; }
        else             { src = Wo; dst = Wob;             }
    }
    long i = base + threadIdx.x * 4;
    float4 v = *(const float4*)(src + i);
    short4 o;
    o.x = bf16_of(v.x); o.y = bf16_of(v.y); o.z = bf16_of(v.z); o.w = bf16_of(v.w);
    *(short4*)(dst + i) = o;
}

// ---------------- GEMM: C[m][n] = sum_k A[m][k] * Bw[n][k] + bias[n] ----------------
// MODE 0 (tile 128x128): QKV epilogue -> fragment-major Qf/Kf/Vf buffers:
//   Qf/Kf: [bh][t/16][d/32][lane(quad*16+lr)][8]  elem: X[t16+lr][d32+quad*8+e]
//   Vf:    [bh][t/32][d/16][lane][8]              elem: V[d16+lr][key perm]
// MODE 1 (tile 64x128): proj epilogue (fp32 out [M,1024])
template<int MODE>
__global__ __launch_bounds__(256) void gemm_bt(
    const short* __restrict__ A, const short* __restrict__ Bw,
    const float* __restrict__ b0, const float* __restrict__ b1, const float* __restrict__ b2,
    short* __restrict__ outQ, short* __restrict__ outK, short* __restrict__ outV,
    float* __restrict__ outP, int K)
{
    constexpr int TM = (MODE == 0) ? 128 : 64;
    constexpr int NI = TM / 32;          // acc row-blocks per wave
    __shared__ short As[TM * 32];
    __shared__ short Bs[128 * 32];
    const int tid  = threadIdx.x;
    const int w    = tid >> 6, lane = tid & 63;
    const int quad = lane >> 4, lr = lane & 15;
    const int wm   = (w & 1) * (TM / 2), wn = (w >> 1) * 64;
    const long m0  = (long)blockIdx.y * TM, n0 = (long)blockIdx.x * 128;

    floatx4 acc[NI][4] = {};

    const int srow = lane >> 2;          // 0..15
    const int scol = (lane & 3) * 8;     // 0,8,16,24
    const short* gA = A  + (m0 + w * 16 + srow) * (long)K + scol;
    const short* gB = Bw + (n0 + w * 16 + srow) * (long)K + scol;

    for (int kt = 0; kt < K; kt += 32) {
        async_copy16(gA + kt,            As + w * 512);
        if (TM == 128) async_copy16(gA + kt + 64L * K,  As + (w + 4) * 512);
        async_copy16(gB + kt,            Bs + w * 512);
        async_copy16(gB + kt + 64L * K,  Bs + (w + 4) * 512);
        __syncthreads();

        const short8* As8 = (const short8*)As;
        const short8* Bs8 = (const short8*)Bs;
        short8 af[NI], bf[4];
#pragma unroll
        for (int i = 0; i < NI; ++i) af[i] = As8[(wm + i * 16 + lr) * 4 + quad];
#pragma unroll
        for (int j = 0; j < 4; ++j) bf[j] = Bs8[(wn + j * 16 + lr) * 4 + quad];
#pragma unroll
        for (int i = 0; i < NI; ++i)
#pragma unroll
            for (int j = 0; j < 4; ++j)
                acc[i][j] = __builtin_amdgcn_mfma_f32_16x16x32_bf16(af[i], bf[j], acc[i][j], 0, 0, 0);
        __syncthreads();
    }

#pragma unroll
    for (int i = 0; i < NI; ++i) {
#pragma unroll
        for (int j = 0; j < 4; ++j) {
#pragma unroll
            for (int r = 0; r < 4; ++r) {
                long m = m0 + wm + i * 16 + quad * 4 + r;   // token index
                long n = n0 + wn + j * 16 + lr;             // output feature
                float v = acc[i][j][r];
                if (MODE == 0) {
                    int sel = (int)(n >> 10);
                    int nn  = (int)(n & 1023);
                    v += (sel == 0 ? b0[nn] : (sel == 1 ? b1[nn] : b2[nn]));
                    int  h  = nn >> 6, d = nn & 63;
                    int  t  = (int)(m & 2047);
                    long bh = (m >> 11) * NHEAD + h;
                    if (sel == 2) {
                        // Vf elem: stage t>>5, dblk d>>4, lane'=( (t>>2)&3 )*16 + (d&15),
                        // e = ((t>>4)&1)*4 + (t&3)
                        long idx = (((long)bh * 64 + (t >> 5)) * 4 + (d >> 4)) * 512
                                 + (((t >> 2) & 3) * 16 + (d & 15)) * 8
                                 + ((t >> 4) & 1) * 4 + (t & 3);
                        outV[idx] = bf16_of(v);
                    } else {
                        // Qf/Kf elem: blk t>>4, c d>>5, lane'=((d>>3)&3)*16 + (t&15), e=d&7
                        long idx = (((long)bh * 128 + (t >> 4)) * 2 + (d >> 5)) * 512
                                 + (((d >> 3) & 3) * 16 + (t & 15)) * 8 + (d & 7);
                        if (sel == 0) outQ[idx] = bf16_of(v * QSCALE);
                        else          outK[idx] = bf16_of(v);
                    }
                } else {
                    v += b0[(int)n];
                    outP[m * N_EMBD + n] = v;
                }
            }
        }
    }
}

// ---------------- flash attention: fragment-major inputs, register-only P ----------------
// Block = (pair p, bh): phases over q-tiles {p, 31-p} -> uniform work.
// 4 waves = 2 q-subtiles (qs) x 2 key-halves (half).
// S^T = mfma(K-frag, Q-frag): D (col=q=lr, row=key=quad*4+r) feeds PV directly.
// All K/V/Q loads are lane*16B coalesced from fragment-major buffers.
__global__ __launch_bounds__(256) void attn_kernel(
    const short* __restrict__ Qf, const short* __restrict__ Kf,
    const short* __restrict__ Vf, short* __restrict__ Y)
{
    __shared__ float Ob[2][32][68];        // half-1 partial O^T (padded)
    __shared__ float Lb[2][32];

    const int tid  = threadIdx.x;
    const int w    = tid >> 6, lane = tid & 63;
    const int quad = lane >> 4, lr = lane & 15;
    const int qs   = w & 1, half = w >> 1;

    const int id = blockIdx.x;
    const int bh = id & 31;
    const int pr = id >> 5;                // 0..15

    const short* Qp = Qf + (long)bh * 131072;
    const short* Kp = Kf + (long)bh * 131072;
    const short* Vp = Vf + (long)bh * 131072;

    const long trow_base = (long)(bh >> 4) * T_SEQ;
    const int  hcol      = (bh & 15) * DKH;

    for (int ph = 0; ph < 2; ++ph) {
        const int qt  = ph ? (31 - pr) : pr;
        const int qrb = qt * 64 + qs * 32;
        const int qb  = qrb >> 4;

        short8 qfv[2][2];
#pragma unroll
        for (int m = 0; m < 2; ++m)
#pragma unroll
            for (int c = 0; c < 2; ++c)
                qfv[m][c] = *(const short8*)(Qp + (long)(((qb + m) * 2 + c) * 512) + lane * 8);

        floatx4 o[2][4] = {};
        float rs[2] = {0.f, 0.f};

        const int S_tot = 2 * qt + qs + 1;
        const int h0 = (S_tot + 1) >> 1;
        const int sb = half ? h0 : 0;
        const int se = half ? S_tot : h0;

        short8 kbn[2][2];
        if (sb < se) {
#pragma unroll
            for (int blk = 0; blk < 2; ++blk)
#pragma unroll
                for (int c = 0; c < 2; ++c)
                    kbn[blk][c] = *(const short8*)(Kp + (long)(((sb * 2 + blk) * 2 + c) * 512) + lane * 8);
        }

        for (int s = sb; s < se; ++s) {
            short8 ka[2][2];
#pragma unroll
            for (int blk = 0; blk < 2; ++blk)
#pragma unroll
                for (int c = 0; c < 2; ++c) ka[blk][c] = kbn[blk][c];
            if (s + 1 < se) {
#pragma unroll
                for (int blk = 0; blk < 2; ++blk)
#pragma unroll
                    for (int c = 0; c < 2; ++c)
                        kbn[blk][c] = *(const short8*)(Kp + (long)((((s + 1) * 2 + blk) * 2 + c) * 512) + lane * 8);
            }
            short8 va[4];
#pragma unroll
            for (int d = 0; d < 4; ++d)
                va[d] = *(const short8*)(Vp + (long)((s * 4 + d) * 512) + lane * 8);

            // S^T = K Q^T
            floatx4 sc[2][2];
#pragma unroll
            for (int m = 0; m < 2; ++m)
#pragma unroll
                for (int blk = 0; blk < 2; ++blk) {
                    floatx4 z = {};
                    z = __builtin_amdgcn_mfma_f32_16x16x32_bf16(ka[blk][0], qfv[m][0], z, 0, 0, 0);
                    z = __builtin_amdgcn_mfma_f32_16x16x32_bf16(ka[blk][1], qfv[m][1], z, 0, 0, 0);
                    sc[m][blk] = z;
                }

            if (s == S_tot - 1) {          // wave-uniform diagonal stage
                const int k0 = s * 32;
#pragma unroll
                for (int m = 0; m < 2; ++m)
#pragma unroll
                    for (int blk = 0; blk < 2; ++blk)
#pragma unroll
                        for (int r = 0; r < 4; ++r) {
                            int key = k0 + blk * 16 + quad * 4 + r;
                            if (key > qrb + m * 16 + lr) sc[m][blk][r] = -INFINITY;
                        }
            }

            // P = exp2(S^T) packed in-register into X-operand fragments
            short8 pa[2];
#pragma unroll
            for (int m = 0; m < 2; ++m) {
                union { short8 v; short e[8]; } pu;
#pragma unroll
                for (int blk = 0; blk < 2; ++blk)
#pragma unroll
                    for (int r = 0; r < 4; ++r) {
                        float p = __builtin_amdgcn_exp2f(sc[m][blk][r]);
                        rs[m] += p;
                        union { float f; unsigned u; } cc; cc.f = p;
                        pu.e[blk * 4 + r] = (short)((cc.u + 0x8000u) >> 16);
                    }
                pa[m] = pu.v;
            }

            // O^T += V^T P
#pragma unroll
            for (int m = 0; m < 2; ++m)
#pragma unroll
                for (int d = 0; d < 4; ++d)
                    o[m][d] = __builtin_amdgcn_mfma_f32_16x16x32_bf16(va[d], pa[m], o[m][d], 0, 0, 0);
        }

        // full row sums (row = q = lr): reduce across quads
#pragma unroll
        for (int m = 0; m < 2; ++m) {
            rs[m] += __shfl_xor(rs[m], 16, 64);
            rs[m] += __shfl_xor(rs[m], 32, 64);
        }

        if (half == 1) {
#pragma unroll
            for (int m = 0; m < 2; ++m) {
#pragma unroll
                for (int d = 0; d < 4; ++d)
                    *(floatx4*)&Ob[qs][m * 16 + lr][d * 16 + quad * 4] = o[m][d];
                Lb[qs][m * 16 + lr] = rs[m];
            }
        }
        __syncthreads();
        if (half == 0) {
#pragma unroll
            for (int m = 0; m < 2; ++m) {
                float l   = rs[m] + Lb[qs][m * 16 + lr];
                float inv = 1.f / l;
                long  yb  = (trow_base + qrb + m * 16 + lr) * N_EMBD + hcol;
#pragma unroll
                for (int d = 0; d < 4; ++d) {
                    floatx4 ob = *(const floatx4*)&Ob[qs][m * 16 + lr][d * 16 + quad * 4];
                    short4v y4;
#pragma unroll
                    for (int r = 0; r < 4; ++r) y4[r] = bf16_of((o[m][d][r] + ob[r]) * inv);
                    *(short4v*)(Y + yb + d * 16 + quad * 4) = y4;
                }
            }
        }
        __syncthreads();
    }
}

extern "C" void kernel_launch(void* const* d_in, const int* in_sizes, int n_in,
                              void* d_out, int out_size, void* d_ws, size_t ws_size,
                              hipStream_t stream) {
    const float* x  = (const float*)d_in[0];
    const float* Wq = (const float*)d_in[1];
    const float* bq = (const float*)d_in[2];
    const float* Wk = (const float*)d_in[3];
    const float* bk = (const float*)d_in[4];
    const float* Wv = (const float*)d_in[5];
    const float* bv = (const float*)d_in[6];
    const float* Wo = (const float*)d_in[7];
    const float* bo = (const float*)d_in[8];
    float* out = (float*)d_out;

    char* ws = (char*)d_ws;
    short* xb    = (short*)(ws);                       // [4096,1024] bf16, 8MB; reused as Yb
    short* Wqkvb = (short*)(ws + (8L  << 20));         // [3072,1024] bf16, 6MB
    short* Wob   = (short*)(ws + (14L << 20));         // [1024,1024] bf16, 2MB
    short* Qb    = (short*)(ws + (16L << 20));         // Qf fragment-major, 8MB
    short* Kbuf  = (short*)(ws + (24L << 20));         // Kf fragment-major, 8MB
    short* Vtb   = (short*)(ws + (32L << 20));         // Vf fragment-major, 8MB
    short* Yb    = xb;                                 // reuse (x dead after QKV GEMM)

    cvt_all<<<8192, 256, 0, stream>>>(x, Wq, Wk, Wv, Wo, xb, Wqkvb, Wob);

    gemm_bt<0><<<dim3(24, 32), 256, 0, stream>>>(xb, Wqkvb, bq, bk, bv,
                                                 Qb, Kbuf, Vtb, nullptr, N_EMBD);
    attn_kernel<<<512, 256, 0, stream>>>(Qb, Kbuf, Vtb, Yb);
    gemm_bt<1><<<dim3(8, 64), 256, 0, stream>>>(Yb, Wob, bo, nullptr, nullptr,
                                                nullptr, nullptr, nullptr, out, N_EMBD);
}

// Round 7
// 184.069 us; speedup vs baseline: 1.4276x; 1.0280x over previous
//
#include <hip/hip_runtime.h>
#include <hip/hip_bf16.h>

#define N_EMBD 1024
#define T_SEQ  2048
#define BATCH  2
#define NHEAD  16
#define DKH    64
#define MTOK   (BATCH * T_SEQ)   // 4096

typedef __attribute__((ext_vector_type(8))) short short8;   // 8 x bf16
typedef __attribute__((ext_vector_type(4))) short short4v;  // 4 x bf16
typedef __attribute__((ext_vector_type(4))) float floatx4;  // MFMA C/D

#define QSCALE 0.18033688011112042f   // 0.125 * log2(e), folded into Q

static __device__ __forceinline__ short bf16_of(float f) {
    union { float f; unsigned u; } x; x.f = f;
    unsigned r = (x.u + 0x7fff + ((x.u >> 16) & 1)) >> 16;
    return (short)r;
}

static __device__ __forceinline__ void async_copy16(const void* g, void* l) {
    __builtin_amdgcn_global_load_lds(
        (const __attribute__((address_space(1))) void*)g,
        (__attribute__((address_space(3))) void*)l,
        16, 0, 0);
}

// ---------------- fused fp32 -> bf16 convert for all 5 tensors ----------------
__global__ __launch_bounds__(256) void cvt_all(
    const float* __restrict__ x,  const float* __restrict__ Wq,
    const float* __restrict__ Wk, const float* __restrict__ Wv,
    const float* __restrict__ Wo,
    short* __restrict__ xb, short* __restrict__ Wqkvb, short* __restrict__ Wob) {
    int b = blockIdx.x;
    const float* src; short* dst; long base;
    if (b < 4096) { src = x; dst = xb; base = (long)b * 1024; }
    else {
        int r   = (b - 4096) >> 10;
        base    = (long)((b - 4096) & 1023) * 1024;
        if (r == 0)      { src = Wq; dst = Wqkvb;           }
        else if (r == 1) { src = Wk; dst = Wqkvb + 1048576; }
        else if (r == 2) { src = Wv; dst = Wqkvb + 2097152; }
        else             { src = Wo; dst = Wob;             }
    }
    long i = base + threadIdx.x * 4;
    float4 v = *(const float4*)(src + i);
    short4 o;
    o.x = bf16_of(v.x); o.y = bf16_of(v.y); o.z = bf16_of(v.z); o.w = bf16_of(v.w);
    *(short4*)(dst + i) = o;
}

// ---------------- QKV GEMM, one launch, 768 blocks ----------------
// id < 512: Q/K, TRANSPOSED orientation (row m = feature of Wq|Wk, col n = token)
//   -> Qf/Kf fragment stores are short4 (e = d&7 contiguous across r)
// id >= 512: V, normal orientation (row m = token, col n = feature of Wv)
//   -> Vf fragment stores are short4 (e = blk*4 + (t&3) contiguous across r)
// NOTE: fragment-buffer block indices use the PER-BATCH token (t & 2047);
// bh already encodes the batch. (r6 bug: used global t -> one-bh-stride shift.)
__global__ __launch_bounds__(256) void gemm_qkv(
    const short* __restrict__ xb, const short* __restrict__ Wqkv,
    const float* __restrict__ bq, const float* __restrict__ bk, const float* __restrict__ bv,
    short* __restrict__ outQ, short* __restrict__ outK, short* __restrict__ outV)
{
    __shared__ short As[128 * 32];
    __shared__ short Bs[128 * 32];
    const int tid  = threadIdx.x;
    const int w    = tid >> 6, lane = tid & 63;
    const int quad = lane >> 4, lr = lane & 15;
    const int wm   = (w & 1) * 64, wn = (w >> 1) * 64;

    const int  id   = blockIdx.x;
    const bool isQK = id < 512;
    long m0, n0;
    const short *Aptr, *Bptr;
    if (isQK) {
        m0 = (long)(id >> 5) * 128;        // feature of [Wq;Wk] (0..2047)
        n0 = (long)(id & 31) * 128;        // token
        Aptr = Wqkv;       Bptr = xb;
    } else {
        int v = id - 512;
        m0 = (long)(v >> 3) * 128;         // token
        n0 = (long)(v & 7) * 128;          // feature of Wv (0..1023)
        Aptr = xb;         Bptr = Wqkv + 2097152;
    }

    floatx4 acc[4][4] = {};

    const int srow = lane >> 2;            // 0..15
    const int scol = (lane & 3) * 8;       // 0,8,16,24
    const short* gA = Aptr + (m0 + w * 16 + srow) * 1024L + scol;
    const short* gB = Bptr + (n0 + w * 16 + srow) * 1024L + scol;

    for (int kt = 0; kt < 1024; kt += 32) {
        async_copy16(gA + kt,              As + w * 512);
        async_copy16(gA + kt + 64L * 1024, As + (w + 4) * 512);
        async_copy16(gB + kt,              Bs + w * 512);
        async_copy16(gB + kt + 64L * 1024, Bs + (w + 4) * 512);
        __syncthreads();

        const short8* As8 = (const short8*)As;
        const short8* Bs8 = (const short8*)Bs;
        short8 af[4], bf[4];
#pragma unroll
        for (int i = 0; i < 4; ++i) af[i] = As8[(wm + i * 16 + lr) * 4 + quad];
#pragma unroll
        for (int j = 0; j < 4; ++j) bf[j] = Bs8[(wn + j * 16 + lr) * 4 + quad];
#pragma unroll
        for (int i = 0; i < 4; ++i)
#pragma unroll
            for (int j = 0; j < 4; ++j)
                acc[i][j] = __builtin_amdgcn_mfma_f32_16x16x32_bf16(af[i], bf[j], acc[i][j], 0, 0, 0);
        __syncthreads();
    }

    if (isQK) {
#pragma unroll
        for (int i = 0; i < 4; ++i) {
#pragma unroll
            for (int j = 0; j < 4; ++j) {
                int f0  = (int)m0 + wm + i * 16 + quad * 4;   // feature base (r=0)
                int t   = (int)n0 + wn + j * 16 + lr;         // global token
                int tb  = t & 2047;                           // per-batch token
                int sel = f0 >> 10;                            // 0=Q, 1=K
                int fb  = f0 & 1023;
                int h   = fb >> 6, d0 = fb & 63;
                long bh = (long)(t >> 11) * NHEAD + h;
                const float* bias = sel ? bk : bq;
                short4v y;
#pragma unroll
                for (int r = 0; r < 4; ++r) {
                    float v = acc[i][j][r] + bias[fb + r];
                    if (sel == 0) v *= QSCALE;
                    y[r] = bf16_of(v);
                }
                long idx = ((bh * 128 + (tb >> 4)) * 2 + (d0 >> 5)) * 512
                         + (((d0 >> 3) & 3) * 16 + (tb & 15)) * 8 + (d0 & 7);
                *(short4v*)((sel ? outK : outQ) + idx) = y;
            }
        }
    } else {
#pragma unroll
        for (int i = 0; i < 4; ++i) {
#pragma unroll
            for (int j = 0; j < 4; ++j) {
                int t0 = (int)m0 + wm + i * 16 + quad * 4;    // global token base (r=0)
                int tb = t0 & 2047;                           // per-batch token
                int n  = (int)n0 + wn + j * 16 + lr;          // Wv feature
                int h  = n >> 6, d = n & 63;
                long bh = (long)(t0 >> 11) * NHEAD + h;
                float bias = bv[n];
                short4v y;
#pragma unroll
                for (int r = 0; r < 4; ++r) y[r] = bf16_of(acc[i][j][r] + bias);
                long idx = ((bh * 64 + (tb >> 5)) * 4 + (d >> 4)) * 512
                         + (((tb >> 2) & 3) * 16 + (d & 15)) * 8 + ((tb >> 4) & 1) * 4;
                *(short4v*)(outV + idx) = y;
            }
        }
    }
}

// ---------------- output projection, transposed (row=outfeature, col=token) ----------------
// 64x128 tile, float4 output stores (out[t][f0..f0+3]).
__global__ __launch_bounds__(256) void gemm_proj(
    const short* __restrict__ Yb, const short* __restrict__ Wo,
    const float* __restrict__ bo, float* __restrict__ out)
{
    __shared__ short As[64 * 32];          // Wo tile (64 out-features)
    __shared__ short Bs[128 * 32];         // Y tile (128 tokens)
    const int tid  = threadIdx.x;
    const int w    = tid >> 6, lane = tid & 63;
    const int quad = lane >> 4, lr = lane & 15;
    const int wm   = (w & 1) * 32, wn = (w >> 1) * 64;
    const long m0  = (long)blockIdx.y * 64;    // out-feature
    const long n0  = (long)blockIdx.x * 128;   // token

    floatx4 acc[2][4] = {};

    const int srow = lane >> 2;
    const int scol = (lane & 3) * 8;
    const short* gA = Wo + (m0 + w * 16 + srow) * 1024L + scol;
    const short* gB = Yb + (n0 + w * 16 + srow) * 1024L + scol;

    for (int kt = 0; kt < 1024; kt += 32) {
        async_copy16(gA + kt,              As + w * 512);
        async_copy16(gB + kt,              Bs + w * 512);
        async_copy16(gB + kt + 64L * 1024, Bs + (w + 4) * 512);
        __syncthreads();

        const short8* As8 = (const short8*)As;
        const short8* Bs8 = (const short8*)Bs;
        short8 af[2], bf[4];
#pragma unroll
        for (int i = 0; i < 2; ++i) af[i] = As8[(wm + i * 16 + lr) * 4 + quad];
#pragma unroll
        for (int j = 0; j < 4; ++j) bf[j] = Bs8[(wn + j * 16 + lr) * 4 + quad];
#pragma unroll
        for (int i = 0; i < 2; ++i)
#pragma unroll
            for (int j = 0; j < 4; ++j)
                acc[i][j] = __builtin_amdgcn_mfma_f32_16x16x32_bf16(af[i], bf[j], acc[i][j], 0, 0, 0);
        __syncthreads();
    }

#pragma unroll
    for (int i = 0; i < 2; ++i) {
#pragma unroll
        for (int j = 0; j < 4; ++j) {
            int  f0 = (int)m0 + wm + i * 16 + quad * 4;
            long t  = n0 + wn + j * 16 + lr;
            float4 o4;
            o4.x = acc[i][j][0] + bo[f0 + 0];
            o4.y = acc[i][j][1] + bo[f0 + 1];
            o4.z = acc[i][j][2] + bo[f0 + 2];
            o4.w = acc[i][j][3] + bo[f0 + 3];
            *(float4*)(out + t * N_EMBD + f0) = o4;
        }
    }
}

// ---------------- flash attention: one q-tile per block, big-first ----------------
// 4 waves = 2 q-subtiles (qs, 32 rows) x 2 key-halves (half).
// S^T = mfma(K-frag, Q-frag) feeds PV directly (register-only P).
// All Q/K/V loads are lane*16B coalesced from fragment-major buffers.
__global__ __launch_bounds__(256) void attn_kernel(
    const short* __restrict__ Qf, const short* __restrict__ Kf,
    const short* __restrict__ Vf, short* __restrict__ Y)
{
    __shared__ float Ob[2][32][68];        // half-1 partial O^T (padded)
    __shared__ float Lb[2][32];

    const int tid  = threadIdx.x;
    const int w    = tid >> 6, lane = tid & 63;
    const int quad = lane >> 4, lr = lane & 15;
    const int qs   = w & 1, half = w >> 1;

    const int id = blockIdx.x;
    const int qt = 31 - (id >> 5);         // big tiles dispatched first
    const int bh = id & 31;

    const short* Qp = Qf + (long)bh * 131072;
    const short* Kp = Kf + (long)bh * 131072;
    const short* Vp = Vf + (long)bh * 131072;

    const int qrb = qt * 64 + qs * 32;
    const int qb  = qrb >> 4;

    short8 qfv[2][2];
#pragma unroll
    for (int m = 0; m < 2; ++m)
#pragma unroll
        for (int c = 0; c < 2; ++c)
            qfv[m][c] = *(const short8*)(Qp + (long)(((qb + m) * 2 + c) * 512) + lane * 8);

    floatx4 o[2][4] = {};
    float rs[2] = {0.f, 0.f};

    const int S_tot = 2 * qt + qs + 1;
    const int h0 = (S_tot + 1) >> 1;
    const int sb = half ? h0 : 0;
    const int se = half ? S_tot : h0;

    short8 kbn[2][2];
    if (sb < se) {
#pragma unroll
        for (int blk = 0; blk < 2; ++blk)
#pragma unroll
            for (int c = 0; c < 2; ++c)
                kbn[blk][c] = *(const short8*)(Kp + (long)(((sb * 2 + blk) * 2 + c) * 512) + lane * 8);
    }

    for (int s = sb; s < se; ++s) {
        short8 ka[2][2];
#pragma unroll
        for (int blk = 0; blk < 2; ++blk)
#pragma unroll
            for (int c = 0; c < 2; ++c) ka[blk][c] = kbn[blk][c];
        if (s + 1 < se) {
#pragma unroll
            for (int blk = 0; blk < 2; ++blk)
#pragma unroll
                for (int c = 0; c < 2; ++c)
                    kbn[blk][c] = *(const short8*)(Kp + (long)((((s + 1) * 2 + blk) * 2 + c) * 512) + lane * 8);
        }
        short8 va[4];
#pragma unroll
        for (int d = 0; d < 4; ++d)
            va[d] = *(const short8*)(Vp + (long)((s * 4 + d) * 512) + lane * 8);

        // S^T = K Q^T
        floatx4 sc[2][2];
#pragma unroll
        for (int m = 0; m < 2; ++m)
#pragma unroll
            for (int blk = 0; blk < 2; ++blk) {
                floatx4 z = {};
                z = __builtin_amdgcn_mfma_f32_16x16x32_bf16(ka[blk][0], qfv[m][0], z, 0, 0, 0);
                z = __builtin_amdgcn_mfma_f32_16x16x32_bf16(ka[blk][1], qfv[m][1], z, 0, 0, 0);
                sc[m][blk] = z;
            }

        if (s == S_tot - 1) {              // wave-uniform diagonal stage
            const int k0 = s * 32;
#pragma unroll
            for (int m = 0; m < 2; ++m)
#pragma unroll
                for (int blk = 0; blk < 2; ++blk)
#pragma unroll
                    for (int r = 0; r < 4; ++r) {
                        int key = k0 + blk * 16 + quad * 4 + r;
                        if (key > qrb + m * 16 + lr) sc[m][blk][r] = -INFINITY;
                    }
        }

        // P = exp2(S^T) packed in-register into operand fragments
        short8 pa[2];
#pragma unroll
        for (int m = 0; m < 2; ++m) {
            union { short8 v; short e[8]; } pu;
#pragma unroll
            for (int blk = 0; blk < 2; ++blk)
#pragma unroll
                for (int r = 0; r < 4; ++r) {
                    float p = __builtin_amdgcn_exp2f(sc[m][blk][r]);
                    rs[m] += p;
                    union { float f; unsigned u; } cc; cc.f = p;
                    pu.e[blk * 4 + r] = (short)((cc.u + 0x8000u) >> 16);
                }
            pa[m] = pu.v;
        }

        // O^T += V^T P
#pragma unroll
        for (int m = 0; m < 2; ++m)
#pragma unroll
            for (int d = 0; d < 4; ++d)
                o[m][d] = __builtin_amdgcn_mfma_f32_16x16x32_bf16(va[d], pa[m], o[m][d], 0, 0, 0);
    }

    // full row sums (row = q = lr): reduce across quads
#pragma unroll
    for (int m = 0; m < 2; ++m) {
        rs[m] += __shfl_xor(rs[m], 16, 64);
        rs[m] += __shfl_xor(rs[m], 32, 64);
    }

    if (half == 1) {
#pragma unroll
        for (int m = 0; m < 2; ++m) {
#pragma unroll
            for (int d = 0; d < 4; ++d)
                *(floatx4*)&Ob[qs][m * 16 + lr][d * 16 + quad * 4] = o[m][d];
            Lb[qs][m * 16 + lr] = rs[m];
        }
    }
    __syncthreads();
    if (half == 0) {
        const long trow0 = (long)(bh >> 4) * T_SEQ + qrb;
        const int  hcol  = (bh & 15) * DKH;
#pragma unroll
        for (int m = 0; m < 2; ++m) {
            float l   = rs[m] + Lb[qs][m * 16 + lr];
            float inv = 1.f / l;
            long  yb  = (trow0 + m * 16 + lr) * N_EMBD + hcol;
#pragma unroll
            for (int d = 0; d < 4; ++d) {
                floatx4 ob = *(const floatx4*)&Ob[qs][m * 16 + lr][d * 16 + quad * 4];
                short4v y4;
#pragma unroll
                for (int r = 0; r < 4; ++r) y4[r] = bf16_of((o[m][d][r] + ob[r]) * inv);
                *(short4v*)(Y + yb + d * 16 + quad * 4) = y4;
            }
        }
    }
}

extern "C" void kernel_launch(void* const* d_in, const int* in_sizes, int n_in,
                              void* d_out, int out_size, void* d_ws, size_t ws_size,
                              hipStream_t stream) {
    const float* x  = (const float*)d_in[0];
    const float* Wq = (const float*)d_in[1];
    const float* bq = (const float*)d_in[2];
    const float* Wk = (const float*)d_in[3];
    const float* bk = (const float*)d_in[4];
    const float* Wv = (const float*)d_in[5];
    const float* bv = (const float*)d_in[6];
    const float* Wo = (const float*)d_in[7];
    const float* bo = (const float*)d_in[8];
    float* out = (float*)d_out;

    char* ws = (char*)d_ws;
    short* xb    = (short*)(ws);                       // [4096,1024] bf16, 8MB; reused as Yb
    short* Wqkvb = (short*)(ws + (8L  << 20));         // [3072,1024] bf16, 6MB
    short* Wob   = (short*)(ws + (14L << 20));         // [1024,1024] bf16, 2MB
    short* Qb    = (short*)(ws + (16L << 20));         // Qf fragment-major, 8MB
    short* Kbuf  = (short*)(ws + (24L << 20));         // Kf fragment-major, 8MB
    short* Vtb   = (short*)(ws + (32L << 20));         // Vf fragment-major, 8MB
    short* Yb    = xb;                                 // reuse (x dead after QKV GEMM)

    cvt_all<<<8192, 256, 0, stream>>>(x, Wq, Wk, Wv, Wo, xb, Wqkvb, Wob);

    gemm_qkv<<<768, 256, 0, stream>>>(xb, Wqkvb, bq, bk, bv, Qb, Kbuf, Vtb);
    attn_kernel<<<1024, 256, 0, stream>>>(Qb, Kbuf, Vtb, Yb);
    gemm_proj<<<dim3(32, 16), 256, 0, stream>>>(Yb, Wob, bo, out);
}

// Round 8
// 173.554 us; speedup vs baseline: 1.5141x; 1.0606x over previous
//
#include <hip/hip_runtime.h>
#include <hip/hip_bf16.h>

#define N_EMBD 1024
#define T_SEQ  2048
#define BATCH  2
#define NHEAD  16
#define DKH    64
#define MTOK   (BATCH * T_SEQ)   // 4096

typedef __attribute__((ext_vector_type(8))) short short8;   // 8 x bf16
typedef __attribute__((ext_vector_type(4))) short short4v;  // 4 x bf16
typedef __attribute__((ext_vector_type(4))) float floatx4;  // MFMA C/D

#define QSCALE 0.18033688011112042f   // 0.125 * log2(e), folded into Q

static __device__ __forceinline__ short bf16_of(float f) {
    union { float f; unsigned u; } x; x.f = f;
    unsigned r = (x.u + 0x7fff + ((x.u >> 16) & 1)) >> 16;
    return (short)r;
}

// Fragment-major layout for a row-major [R][1024] bf16 matrix:
//   elem (row, k) -> ((row>>4)*32 + (k>>5))*512 + (((k>>3)&3)*16 + (row&15))*8 + (k&7)
// i.e. one MFMA operand fragment (16 rows x 32 k) = 512 contiguous shorts,
// loadable as lane*16B fully-coalesced dwordx4.

// ---------------- fp32 -> bf16 fragment-major convert, all 5 tensors ----------------
// 512 blocks: [0,256) x ; [256,320) Wq ; [320,384) Wk (dst rows +1024) ;
// [384,448) Wv ; [448,512) Wo.  Block = one 16-row rowblk x 1024 k.
__global__ __launch_bounds__(256) void cvt_frag(
    const float* __restrict__ x,  const float* __restrict__ Wq,
    const float* __restrict__ Wk, const float* __restrict__ Wv,
    const float* __restrict__ Wo,
    short* __restrict__ xf, short* __restrict__ wqkf,
    short* __restrict__ wvf, short* __restrict__ wof)
{
    int b = blockIdx.x;
    const float* src; short* dst; int srb, drb;
    if (b < 256)      { src = x;  dst = xf;   srb = b;       drb = srb; }
    else if (b < 320) { src = Wq; dst = wqkf; srb = b - 256; drb = srb; }
    else if (b < 384) { src = Wk; dst = wqkf; srb = b - 320; drb = srb + 64; }
    else if (b < 448) { src = Wv; dst = wvf;  srb = b - 384; drb = srb; }
    else              { src = Wo; dst = wof;  srb = b - 448; drb = srb; }

    const int row16 = threadIdx.x >> 4;          // 0..15
    const int kseg  = (threadIdx.x & 15) * 64;   // k base (64 elems per thread)
    const float* sp = src + ((long)srb * 16 + row16) * 1024 + kseg;
    short* dp       = dst + ((long)drb * 32 + (kseg >> 5)) * 512 + row16 * 8;

#pragma unroll
    for (int c = 0; c < 8; ++c) {
        float4 v0 = *(const float4*)(sp + c * 8);
        float4 v1 = *(const float4*)(sp + c * 8 + 4);
        short8 o;
        o[0] = bf16_of(v0.x); o[1] = bf16_of(v0.y); o[2] = bf16_of(v0.z); o[3] = bf16_of(v0.w);
        o[4] = bf16_of(v1.x); o[5] = bf16_of(v1.y); o[6] = bf16_of(v1.z); o[7] = bf16_of(v1.w);
        *(short8*)(dp + (c >> 2) * 512 + (c & 3) * 128) = o;
    }
}

// K-loop: per-wave 64x128 tile, register ping-pong prefetch, no LDS/barriers.
#define GEMM_KLOOP(Ab, Bb)                                                     \
    floatx4 acc[4][8] = {};                                                    \
    short8 a0[4], a1[4], b0[8], b1[8];                                         \
    _Pragma("unroll") for (int i = 0; i < 4; ++i)                              \
        a0[i] = *(const short8*)(Ab + (long)i * 32 * 512);                     \
    _Pragma("unroll") for (int j = 0; j < 8; ++j)                              \
        b0[j] = *(const short8*)(Bb + (long)j * 32 * 512);                     \
    for (int kc = 0; kc < 32; kc += 2) {                                       \
        _Pragma("unroll") for (int i = 0; i < 4; ++i)                          \
            a1[i] = *(const short8*)(Ab + ((long)i * 32 + kc + 1) * 512);      \
        _Pragma("unroll") for (int j = 0; j < 8; ++j)                          \
            b1[j] = *(const short8*)(Bb + ((long)j * 32 + kc + 1) * 512);      \
        _Pragma("unroll") for (int i = 0; i < 4; ++i)                          \
            _Pragma("unroll") for (int j = 0; j < 8; ++j)                      \
                acc[i][j] = __builtin_amdgcn_mfma_f32_16x16x32_bf16(           \
                    a0[i], b0[j], acc[i][j], 0, 0, 0);                         \
        if (kc + 2 < 32) {                                                     \
            _Pragma("unroll") for (int i = 0; i < 4; ++i)                      \
                a0[i] = *(const short8*)(Ab + ((long)i * 32 + kc + 2) * 512);  \
            _Pragma("unroll") for (int j = 0; j < 8; ++j)                      \
                b0[j] = *(const short8*)(Bb + ((long)j * 32 + kc + 2) * 512);  \
        }                                                                      \
        _Pragma("unroll") for (int i = 0; i < 4; ++i)                          \
            _Pragma("unroll") for (int j = 0; j < 8; ++j)                      \
                acc[i][j] = __builtin_amdgcn_mfma_f32_16x16x32_bf16(           \
                    a1[i], b1[j], acc[i][j], 0, 0, 0);                         \
    }

// ---------------- QKV GEMM: 1536 single-wave blocks, no LDS ----------------
// wid < 1024: Q/K transposed (rows = Wqk feature 64, cols = token 128)
// wid >= 1024: V normal (rows = token 64, cols = Wv feature 128)
__global__ __launch_bounds__(64, 2) void gemm_qkv(
    const short* __restrict__ xf, const short* __restrict__ wqkf,
    const short* __restrict__ wvf,
    const float* __restrict__ bq, const float* __restrict__ bk, const float* __restrict__ bv,
    short* __restrict__ outQ, short* __restrict__ outK, short* __restrict__ outV)
{
    const int lane = threadIdx.x & 63;
    const int quad = lane >> 4, lr = lane & 15;
    const int wid  = blockIdx.x;
    const bool isQK = wid < 1024;
    int mw, nw;
    const short *Af, *Bf;
    if (isQK) { mw = (wid >> 5) * 64;          nw = (wid & 31) * 128; Af = wqkf; Bf = xf; }
    else      { int v = wid - 1024;
                mw = (v >> 3) * 64;            nw = (v & 7) * 128;    Af = xf;   Bf = wvf; }

    const short* Ab = Af + (long)(mw >> 4) * 32 * 512 + lane * 8;
    const short* Bb = Bf + (long)(nw >> 4) * 32 * 512 + lane * 8;

    GEMM_KLOOP(Ab, Bb)

    if (isQK) {
#pragma unroll
        for (int i = 0; i < 4; ++i) {
#pragma unroll
            for (int j = 0; j < 8; ++j) {
                int f0  = mw + i * 16 + quad * 4;      // feature of [Wq;Wk]
                int t   = nw + j * 16 + lr;            // global token
                int tb  = t & 2047;
                int sel = f0 >> 10;                    // 0=Q, 1=K
                int fb  = f0 & 1023;
                int h   = fb >> 6, d0 = fb & 63;
                long bh = (long)(t >> 11) * NHEAD + h;
                float4 bias = *(const float4*)((sel ? bk : bq) + fb);
                short4v y;
#pragma unroll
                for (int r = 0; r < 4; ++r) {
                    float v = acc[i][j][r] + (&bias.x)[r];
                    if (sel == 0) v *= QSCALE;
                    y[r] = bf16_of(v);
                }
                long idx = ((bh * 128 + (tb >> 4)) * 2 + (d0 >> 5)) * 512
                         + (((d0 >> 3) & 3) * 16 + (tb & 15)) * 8 + (d0 & 7);
                *(short4v*)((sel ? outK : outQ) + idx) = y;
            }
        }
    } else {
#pragma unroll
        for (int i = 0; i < 4; ++i) {
#pragma unroll
            for (int j = 0; j < 8; ++j) {
                int t0 = mw + i * 16 + quad * 4;       // global token base
                int tb = t0 & 2047;
                int d  = nw + j * 16 + lr;             // Wv feature
                int h  = d >> 6, dblk = (d >> 4) & 3;
                long bh = (long)(t0 >> 11) * NHEAD + h;
                float bias = bv[d];
                short4v y;
#pragma unroll
                for (int r = 0; r < 4; ++r) y[r] = bf16_of(acc[i][j][r] + bias);
                long idx = ((bh * 64 + (tb >> 5)) * 4 + dblk) * 512
                         + lane * 8 + (i & 1) * 4;
                *(short4v*)(outV + idx) = y;
            }
        }
    }
}

// ---------------- output projection: 512 single-wave blocks, no LDS ----------------
// Transposed (rows = out-feature 64, cols = token 128); float4 stores.
__global__ __launch_bounds__(64, 2) void gemm_proj(
    const short* __restrict__ Yf, const short* __restrict__ wof,
    const float* __restrict__ bo, float* __restrict__ out)
{
    const int lane = threadIdx.x & 63;
    const int quad = lane >> 4, lr = lane & 15;
    const int wid  = blockIdx.x;
    const int mw   = (wid >> 5) * 64;     // out-feature
    const int nw   = (wid & 31) * 128;    // token

    const short* Ab = wof + (long)(mw >> 4) * 32 * 512 + lane * 8;
    const short* Bb = Yf  + (long)(nw >> 4) * 32 * 512 + lane * 8;

    GEMM_KLOOP(Ab, Bb)

#pragma unroll
    for (int i = 0; i < 4; ++i) {
#pragma unroll
        for (int j = 0; j < 8; ++j) {
            int  f0 = mw + i * 16 + quad * 4;
            long t  = nw + j * 16 + lr;
            float4 b4 = *(const float4*)(bo + f0);
            float4 o4;
            o4.x = acc[i][j][0] + b4.x;
            o4.y = acc[i][j][1] + b4.y;
            o4.z = acc[i][j][2] + b4.z;
            o4.w = acc[i][j][3] + b4.w;
            *(float4*)(out + t * N_EMBD + f0) = o4;
        }
    }
}

// ---------------- flash attention (unchanged core); epilogue -> fragment-major Y ----------------
__global__ __launch_bounds__(256) void attn_kernel(
    const short* __restrict__ Qf, const short* __restrict__ Kf,
    const short* __restrict__ Vf, short* __restrict__ Y)
{
    __shared__ float Ob[2][32][68];
    __shared__ float Lb[2][32];

    const int tid  = threadIdx.x;
    const int w    = tid >> 6, lane = tid & 63;
    const int quad = lane >> 4, lr = lane & 15;
    const int qs   = w & 1, half = w >> 1;

    const int id = blockIdx.x;
    const int qt = 31 - (id >> 5);
    const int bh = id & 31;

    const short* Qp = Qf + (long)bh * 131072;
    const short* Kp = Kf + (long)bh * 131072;
    const short* Vp = Vf + (long)bh * 131072;

    const int qrb = qt * 64 + qs * 32;
    const int qb  = qrb >> 4;

    short8 qfv[2][2];
#pragma unroll
    for (int m = 0; m < 2; ++m)
#pragma unroll
        for (int c = 0; c < 2; ++c)
            qfv[m][c] = *(const short8*)(Qp + (long)(((qb + m) * 2 + c) * 512) + lane * 8);

    floatx4 o[2][4] = {};
    float rs[2] = {0.f, 0.f};

    const int S_tot = 2 * qt + qs + 1;
    const int h0 = (S_tot + 1) >> 1;
    const int sb = half ? h0 : 0;
    const int se = half ? S_tot : h0;

    short8 kbn[2][2];
    if (sb < se) {
#pragma unroll
        for (int blk = 0; blk < 2; ++blk)
#pragma unroll
            for (int c = 0; c < 2; ++c)
                kbn[blk][c] = *(const short8*)(Kp + (long)(((sb * 2 + blk) * 2 + c) * 512) + lane * 8);
    }

    for (int s = sb; s < se; ++s) {
        short8 ka[2][2];
#pragma unroll
        for (int blk = 0; blk < 2; ++blk)
#pragma unroll
            for (int c = 0; c < 2; ++c) ka[blk][c] = kbn[blk][c];
        if (s + 1 < se) {
#pragma unroll
            for (int blk = 0; blk < 2; ++blk)
#pragma unroll
                for (int c = 0; c < 2; ++c)
                    kbn[blk][c] = *(const short8*)(Kp + (long)((((s + 1) * 2 + blk) * 2 + c) * 512) + lane * 8);
        }
        short8 va[4];
#pragma unroll
        for (int d = 0; d < 4; ++d)
            va[d] = *(const short8*)(Vp + (long)((s * 4 + d) * 512) + lane * 8);

        floatx4 sc[2][2];
#pragma unroll
        for (int m = 0; m < 2; ++m)
#pragma unroll
            for (int blk = 0; blk < 2; ++blk) {
                floatx4 z = {};
                z = __builtin_amdgcn_mfma_f32_16x16x32_bf16(ka[blk][0], qfv[m][0], z, 0, 0, 0);
                z = __builtin_amdgcn_mfma_f32_16x16x32_bf16(ka[blk][1], qfv[m][1], z, 0, 0, 0);
                sc[m][blk] = z;
            }

        if (s == S_tot - 1) {
            const int k0 = s * 32;
#pragma unroll
            for (int m = 0; m < 2; ++m)
#pragma unroll
                for (int blk = 0; blk < 2; ++blk)
#pragma unroll
                    for (int r = 0; r < 4; ++r) {
                        int key = k0 + blk * 16 + quad * 4 + r;
                        if (key > qrb + m * 16 + lr) sc[m][blk][r] = -INFINITY;
                    }
        }

        short8 pa[2];
#pragma unroll
        for (int m = 0; m < 2; ++m) {
            union { short8 v; short e[8]; } pu;
#pragma unroll
            for (int blk = 0; blk < 2; ++blk)
#pragma unroll
                for (int r = 0; r < 4; ++r) {
                    float p = __builtin_amdgcn_exp2f(sc[m][blk][r]);
                    rs[m] += p;
                    union { float f; unsigned u; } cc; cc.f = p;
                    pu.e[blk * 4 + r] = (short)((cc.u + 0x8000u) >> 16);
                }
            pa[m] = pu.v;
        }

#pragma unroll
        for (int m = 0; m < 2; ++m)
#pragma unroll
            for (int d = 0; d < 4; ++d)
                o[m][d] = __builtin_amdgcn_mfma_f32_16x16x32_bf16(va[d], pa[m], o[m][d], 0, 0, 0);
    }

#pragma unroll
    for (int m = 0; m < 2; ++m) {
        rs[m] += __shfl_xor(rs[m], 16, 64);
        rs[m] += __shfl_xor(rs[m], 32, 64);
    }

    if (half == 1) {
#pragma unroll
        for (int m = 0; m < 2; ++m) {
#pragma unroll
            for (int d = 0; d < 4; ++d)
                *(floatx4*)&Ob[qs][m * 16 + lr][d * 16 + quad * 4] = o[m][d];
            Lb[qs][m * 16 + lr] = rs[m];
        }
    }
    __syncthreads();
    if (half == 0) {
        // write Y fragment-major over GLOBAL tokens: rowblk = (bh>>4)*128 + qb + m
        const long rb0 = (long)(bh >> 4) * 128 + qb;
        const int  hk  = (bh & 15) * DKH;           // k base for this head
#pragma unroll
        for (int m = 0; m < 2; ++m) {
            float l   = rs[m] + Lb[qs][m * 16 + lr];
            float inv = 1.f / l;
            long  rb  = rb0 + m;
#pragma unroll
            for (int d = 0; d < 4; ++d) {
                floatx4 ob = *(const floatx4*)&Ob[qs][m * 16 + lr][d * 16 + quad * 4];
                short4v y4;
#pragma unroll
                for (int r = 0; r < 4; ++r) y4[r] = bf16_of((o[m][d][r] + ob[r]) * inv);
                int kb = hk + d * 16 + quad * 4;
                long idx = (rb * 32 + (kb >> 5)) * 512
                         + (((kb >> 3) & 3) * 16 + lr) * 8 + (quad & 1) * 4;
                *(short4v*)(Y + idx) = y4;
            }
        }
    }
}

extern "C" void kernel_launch(void* const* d_in, const int* in_sizes, int n_in,
                              void* d_out, int out_size, void* d_ws, size_t ws_size,
                              hipStream_t stream) {
    const float* x  = (const float*)d_in[0];
    const float* Wq = (const float*)d_in[1];
    const float* bq = (const float*)d_in[2];
    const float* Wk = (const float*)d_in[3];
    const float* bk = (const float*)d_in[4];
    const float* Wv = (const float*)d_in[5];
    const float* bv = (const float*)d_in[6];
    const float* Wo = (const float*)d_in[7];
    const float* bo = (const float*)d_in[8];
    float* out = (float*)d_out;

    char* ws = (char*)d_ws;
    short* xf   = (short*)(ws);                      // x frag-major, 8MB; reused as Yf
    short* wqkf = (short*)(ws + (8L  << 20));        // [Wq;Wk] frag-major, 4MB
    short* wvf  = (short*)(ws + (12L << 20));        // Wv frag-major, 2MB
    short* wof  = (short*)(ws + (14L << 20));        // Wo frag-major, 2MB
    short* Qb   = (short*)(ws + (16L << 20));        // Qf, 8MB (pre-scaled)
    short* Kbuf = (short*)(ws + (24L << 20));        // Kf, 8MB
    short* Vtb  = (short*)(ws + (32L << 20));        // Vf, 8MB
    short* Yf   = xf;                                // reuse (x dead after QKV GEMM)

    cvt_frag<<<512, 256, 0, stream>>>(x, Wq, Wk, Wv, Wo, xf, wqkf, wvf, wof);

    gemm_qkv<<<1536, 64, 0, stream>>>(xf, wqkf, wvf, bq, bk, bv, Qb, Kbuf, Vtb);
    attn_kernel<<<1024, 256, 0, stream>>>(Qb, Kbuf, Vtb, Yf);
    gemm_proj<<<512, 64, 0, stream>>>(Yf, wof, bo, out);
}